// Round 5
// baseline (39.970 us; speedup 1.0000x reference)
//
#include <hip/hip_runtime.h>
#include <hip/hip_bf16.h>

typedef __attribute__((ext_vector_type(8))) short short8;
typedef __attribute__((ext_vector_type(4))) float f32x4;
typedef __attribute__((ext_vector_type(4))) unsigned int u32x4;
typedef __attribute__((ext_vector_type(2))) unsigned int u32x2;

#define NN 1024

#define LFENCE { asm volatile("s_waitcnt lgkmcnt(0)" ::: "memory"); __builtin_amdgcn_sched_barrier(0); }

// Round-2/4-verified layout: element index = (row*64 + lane) ^ ((row&7)<<3)
#define ROW_W(ROW, VAL) { \
  float v_ = fmaxf((VAL), 0.0f); \
  __hip_bfloat16 hb_ = __float2bfloat16(v_); \
  wb[((ROW) * 64) + (lane ^ ((((ROW)) & 7) << 3))] = *(short*)&hb_; \
}

#define ROW6(R, BX) \
  ROW_W((R)+0,(BX)+T0_) ROW_W((R)+1,(BX)+T1_) ROW_W((R)+2,(BX)+T2_) \
  ROW_W((R)+3,(BX)+T3_) ROW_W((R)+4,(BX)+T4_) ROW_W((R)+5,(BX)+T5_)

// One supergroup (36 rows at rows 0..35 of this wave's buffer).
#define SGR(A0,A1,A2, M0,M1,M2) do { \
  const float f0_ = b1v + P[(A0)*6+0]; \
  const float f1_ = b1v + P[(A1)*6+0]; \
  const float f2_ = b1v + P[(A2)*6+0]; \
  const float g12_ = P[(A1)*6+1] + P[(A2)*6+2]; \
  const float g21_ = P[(A2)*6+1] + P[(A1)*6+2]; \
  const float g02_ = P[(A0)*6+1] + P[(A2)*6+2]; \
  const float g20_ = P[(A2)*6+1] + P[(A0)*6+2]; \
  const float g01_ = P[(A0)*6+1] + P[(A1)*6+2]; \
  const float g10_ = P[(A1)*6+1] + P[(A0)*6+2]; \
  const float e0_ = P[(M0)*6+3], e1_ = P[(M1)*6+3], e2_ = P[(M2)*6+3]; \
  const float h12_ = P[(M1)*6+4] + P[(M2)*6+5]; \
  const float h21_ = P[(M2)*6+4] + P[(M1)*6+5]; \
  const float h02_ = P[(M0)*6+4] + P[(M2)*6+5]; \
  const float h20_ = P[(M2)*6+4] + P[(M0)*6+5]; \
  const float h01_ = P[(M0)*6+4] + P[(M1)*6+5]; \
  const float h10_ = P[(M1)*6+4] + P[(M0)*6+5]; \
  const float T0_ = e0_+h12_, T1_ = e0_+h21_, T2_ = e1_+h02_; \
  const float T3_ = e1_+h20_, T4_ = e2_+h01_, T5_ = e2_+h10_; \
  const float B0_ = f0_+g12_, B1_ = f0_+g21_, B2_ = f1_+g02_; \
  const float B3_ = f1_+g20_, B4_ = f2_+g01_, B5_ = f2_+g10_; \
  ROW6(0,  B0_) ROW6(6,  B1_) ROW6(12, B2_) \
  ROW6(18, B3_) ROW6(24, B4_) ROW6(30, B5_) \
} while(0)

#define MFMA8(A0_, A1_) do { \
  f32x4 c0_ = {b2v0,b2v0,b2v0,b2v0}; \
  f32x4 c1_ = {b2v1,b2v1,b2v1,b2v1}; \
  c0_ = __builtin_amdgcn_mfma_f32_16x16x32_bf16(A0_, bh00, c0_, 0,0,0); \
  c0_ = __builtin_amdgcn_mfma_f32_16x16x32_bf16(A1_, bh10, c0_, 0,0,0); \
  c0_ = __builtin_amdgcn_mfma_f32_16x16x32_bf16(A0_, bl00, c0_, 0,0,0); \
  c0_ = __builtin_amdgcn_mfma_f32_16x16x32_bf16(A1_, bl10, c0_, 0,0,0); \
  c1_ = __builtin_amdgcn_mfma_f32_16x16x32_bf16(A0_, bh01, c1_, 0,0,0); \
  c1_ = __builtin_amdgcn_mfma_f32_16x16x32_bf16(A1_, bh11, c1_, 0,0,0); \
  c1_ = __builtin_amdgcn_mfma_f32_16x16x32_bf16(A0_, bl01, c1_, 0,0,0); \
  c1_ = __builtin_amdgcn_mfma_f32_16x16x32_bf16(A1_, bl11, c1_, 0,0,0); \
  acc0[0]+=fmaxf(c0_[0],0.f); acc0[1]+=fmaxf(c0_[1],0.f); \
  acc0[2]+=fmaxf(c0_[2],0.f); acc0[3]+=fmaxf(c0_[3],0.f); \
  acc1[0]+=fmaxf(c1_[0],0.f); acc1[1]+=fmaxf(c1_[1],0.f); \
  acc1[2]+=fmaxf(c1_[2],0.f); acc1[3]+=fmaxf(c1_[3],0.f); \
} while(0)

// 48 rows = 3 M-tiles (rows 36..47 are permanently zero -> corrected later).
#define PHASEB3 do { \
  LFENCE; \
  _Pragma("unroll") \
  for (int t_ = 0; t_ < 3; ++t_) { \
    short8 A0_ = *(const short8*)&wb[t_ * 1024 + e0i]; \
    short8 A1_ = *(const short8*)&wb[t_ * 1024 + e1i]; \
    MFMA8(A0_, A1_); \
  } \
} while(0)

// One chunk: build 36 rows, fence, 3-tile MFMA.
#define CH1(A0,A1,A2, M0,M1,M2) do { SGR(A0,A1,A2, M0,M1,M2); PHASEB3; } while(0)

#define MKB(dst_h, dst_l, KH, NIDX) do { \
  _Pragma("unroll") \
  for (int e_ = 0; e_ < 8; ++e_) { \
    float f_ = W2[((KH)*32 + kg*8 + e_)*32 + 16*(NIDX) + colb]; \
    __hip_bfloat16 hi_ = __float2bfloat16(f_); \
    float lof_ = f_ - __bfloat162float(hi_); \
    __hip_bfloat16 lo_ = __float2bfloat16(lof_); \
    dst_h[e_] = *(short*)&hi_; dst_l[e_] = *(short*)&lo_; \
  } \
} while(0)

__global__ __launch_bounds__(256, 4) void symm_mlp_kernel(
    const float* __restrict__ x,
    const float* __restrict__ W1, const float* __restrict__ b1,
    const float* __restrict__ W2, const float* __restrict__ b2,
    const float* __restrict__ W3, const float* __restrict__ b3,
    const int* __restrict__ idx, const int* __restrict__ perms,
    float* __restrict__ out)
{
    __shared__ short h1s[4][48 * 64];     // per-wave 48-row buffer (6144 B each)
    __shared__ float redbuf[4][32];

    const int tid   = threadIdx.x;
    const int lane  = tid & 63;
    const int wv    = tid >> 6;
    const int batch = blockIdx.x;

    // ---- per-lane P[k*6+j] = pts[k] . W1[3j:3j+3, h=lane] (all registers) ----
    float P[36];
    {
        float w1c[18];
        #pragma unroll
        for (int r = 0; r < 18; ++r) w1c[r] = W1[r * 64 + lane];

        float px[6][3];
        #pragma unroll
        for (int k = 0; k < 6; ++k) {
            int p = idx[batch * 6 + k];
            #pragma unroll
            for (int d = 0; d < 3; ++d) px[k][d] = x[(batch * NN + p) * 3 + d];
        }
        #pragma unroll
        for (int k = 0; k < 6; ++k)
        #pragma unroll
        for (int j = 0; j < 6; ++j)
            P[k*6+j] = fmaf(px[k][2], w1c[3*j+2], fmaf(px[k][1], w1c[3*j+1], px[k][0] * w1c[3*j+0]));
    }
    const float b1v = b1[lane];

    // ---- W2 B-fragments (hi+lo bf16 split) ----
    const int colb = lane & 15, kg = lane >> 4;
    short8 bh00, bl00, bh10, bl10, bh01, bl01, bh11, bl11;
    MKB(bh00, bl00, 0, 0);
    MKB(bh10, bl10, 1, 0);
    MKB(bh01, bl01, 0, 1);
    MKB(bh11, bl11, 1, 1);
    const float b2v0 = b2[colb];
    const float b2v1 = b2[16 + colb];

    // ---- zero the pad rows 36..47 of this wave's buffer (stays zero all kernel) ----
    short* wb = &h1s[wv][0];
    *reinterpret_cast<u32x4*>(&wb[2304 + lane * 8]) = u32x4{0u, 0u, 0u, 0u};  // bytes 4608..5632
    *reinterpret_cast<u32x2*>(&wb[2816 + lane * 4]) = u32x2{0u, 0u};          // bytes 5632..6144

    // A-fragment bases (t-invariant swizzle: 16t = 0 mod 8)
    const int Xl  = (lane & 7) << 3;
    const int e0i = (lane & 15) * 64 + ((kg * 8) ^ Xl);
    const int e1i = (lane & 15) * 64 + ((32 + kg * 8) ^ Xl);

    f32x4 acc0 = {0.f,0.f,0.f,0.f}, acc1 = {0.f,0.f,0.f,0.f};

    // ---- 5 supergroups per wave (all 20 covered exactly once) ----
    if (wv == 0) {
        CH1(0,1,2, 3,4,5);  CH1(0,1,3, 2,4,5);  CH1(0,1,4, 2,3,5);
        CH1(0,1,5, 2,3,4);  CH1(0,2,3, 1,4,5);
    } else if (wv == 1) {
        CH1(0,2,4, 1,3,5);  CH1(0,2,5, 1,3,4);  CH1(0,3,4, 1,2,5);
        CH1(0,3,5, 1,2,4);  CH1(0,4,5, 1,2,3);
    } else if (wv == 2) {
        CH1(1,2,3, 0,4,5);  CH1(1,2,4, 0,3,5);  CH1(1,2,5, 0,3,4);
        CH1(1,3,4, 0,2,5);  CH1(1,3,5, 0,2,4);
    } else {
        CH1(1,4,5, 0,2,3);  CH1(2,3,4, 0,1,5);  CH1(2,3,5, 0,1,4);
        CH1(2,4,5, 0,1,3);  CH1(3,4,5, 0,1,2);
    }

    // ---- wave-level reduce (sum over this wave's 180 real + 60 pad rows) ----
    float s0 = acc0[0] + acc0[1] + acc0[2] + acc0[3];
    float s1 = acc1[0] + acc1[1] + acc1[2] + acc1[3];
    s0 += __shfl_xor(s0, 16, 64);  s0 += __shfl_xor(s0, 32, 64);
    s1 += __shfl_xor(s1, 16, 64);  s1 += __shfl_xor(s1, 32, 64);
    // pad rows contributed relu(b2[col]) each: 5 chunks x 12 rows = 60
    s0 -= 60.0f * fmaxf(b2v0, 0.0f);
    s1 -= 60.0f * fmaxf(b2v1, 0.0f);

    if (lane < 16)       redbuf[wv][lane]      = s0;
    else if (lane < 32)  redbuf[wv][lane]      = s1;   // lane-16 -> col 16+(lane&15)
    __syncthreads();

    // ---- combine waves + layer 3, once per batch ----
    if (tid < 40) {
        float m[32];
        #pragma unroll
        for (int c = 0; c < 32; ++c)
            m[c] = (redbuf[0][c] + redbuf[1][c] + redbuf[2][c] + redbuf[3][c]) * (1.0f / 720.0f);
        float y = b3[tid];
        #pragma unroll
        for (int c = 0; c < 32; ++c) y = fmaf(m[c], W3[c * 40 + tid], y);
        out[batch * 40 + tid] = y;
    }
}

extern "C" void kernel_launch(void* const* d_in, const int* in_sizes, int n_in,
                              void* d_out, int out_size, void* d_ws, size_t ws_size,
                              hipStream_t stream) {
    const float* x  = (const float*)d_in[0];
    const float* W1 = (const float*)d_in[1];
    const float* b1 = (const float*)d_in[2];
    const float* W2 = (const float*)d_in[3];
    const float* b2 = (const float*)d_in[4];
    const float* W3 = (const float*)d_in[5];
    const float* b3 = (const float*)d_in[6];
    const int* idx   = (const int*)d_in[7];
    const int* perms = (const int*)d_in[8];
    (void)perms;  // compile-time constant (all perms of 0..5, mean is order-invariant)
    float* out = (float*)d_out;

    symm_mlp_kernel<<<1024, 256, 0, stream>>>(x, W1, b1, W2, b2, W3, b3, idx, perms, out);
}

// Round 6
// 21.359 us; speedup vs baseline: 1.8713x; 1.8713x over previous
//
#include <hip/hip_runtime.h>
#include <hip/hip_bf16.h>

typedef __attribute__((ext_vector_type(8))) short short8;
typedef __attribute__((ext_vector_type(4))) float f32x4;
typedef __attribute__((ext_vector_type(4))) unsigned int u32x4;
typedef __attribute__((ext_vector_type(2))) unsigned int u32x2;

#define NN 1024

#define LFENCE { asm volatile("s_waitcnt lgkmcnt(0)" ::: "memory"); __builtin_amdgcn_sched_barrier(0); }

// Round-2/4-verified layout: element index = (row*64 + lane) ^ ((row&7)<<3)
#define ROW_W(ROW, VAL) { \
  float v_ = fmaxf((VAL), 0.0f); \
  __hip_bfloat16 hb_ = __float2bfloat16(v_); \
  wb[((ROW) * 64) + (lane ^ ((((ROW)) & 7) << 3))] = *(short*)&hb_; \
}

#define ROW6(R, BX) \
  ROW_W((R)+0,(BX)+T0_) ROW_W((R)+1,(BX)+T1_) ROW_W((R)+2,(BX)+T2_) \
  ROW_W((R)+3,(BX)+T3_) ROW_W((R)+4,(BX)+T4_) ROW_W((R)+5,(BX)+T5_)

// One supergroup (36 rows at rows 0..35 of this wave's buffer).
#define SGR(A0,A1,A2, M0,M1,M2) do { \
  const float f0_ = b1v + P[(A0)*6+0]; \
  const float f1_ = b1v + P[(A1)*6+0]; \
  const float f2_ = b1v + P[(A2)*6+0]; \
  const float g12_ = P[(A1)*6+1] + P[(A2)*6+2]; \
  const float g21_ = P[(A2)*6+1] + P[(A1)*6+2]; \
  const float g02_ = P[(A0)*6+1] + P[(A2)*6+2]; \
  const float g20_ = P[(A2)*6+1] + P[(A0)*6+2]; \
  const float g01_ = P[(A0)*6+1] + P[(A1)*6+2]; \
  const float g10_ = P[(A1)*6+1] + P[(A0)*6+2]; \
  const float e0_ = P[(M0)*6+3], e1_ = P[(M1)*6+3], e2_ = P[(M2)*6+3]; \
  const float h12_ = P[(M1)*6+4] + P[(M2)*6+5]; \
  const float h21_ = P[(M2)*6+4] + P[(M1)*6+5]; \
  const float h02_ = P[(M0)*6+4] + P[(M2)*6+5]; \
  const float h20_ = P[(M2)*6+4] + P[(M0)*6+5]; \
  const float h01_ = P[(M0)*6+4] + P[(M1)*6+5]; \
  const float h10_ = P[(M1)*6+4] + P[(M0)*6+5]; \
  const float T0_ = e0_+h12_, T1_ = e0_+h21_, T2_ = e1_+h02_; \
  const float T3_ = e1_+h20_, T4_ = e2_+h01_, T5_ = e2_+h10_; \
  const float B0_ = f0_+g12_, B1_ = f0_+g21_, B2_ = f1_+g02_; \
  const float B3_ = f1_+g20_, B4_ = f2_+g01_, B5_ = f2_+g10_; \
  ROW6(0,  B0_) ROW6(6,  B1_) ROW6(12, B2_) \
  ROW6(18, B3_) ROW6(24, B4_) ROW6(30, B5_) \
} while(0)

#define MFMA8(A0_, A1_) do { \
  f32x4 c0_ = {b2v0,b2v0,b2v0,b2v0}; \
  f32x4 c1_ = {b2v1,b2v1,b2v1,b2v1}; \
  c0_ = __builtin_amdgcn_mfma_f32_16x16x32_bf16(A0_, bh00, c0_, 0,0,0); \
  c0_ = __builtin_amdgcn_mfma_f32_16x16x32_bf16(A1_, bh10, c0_, 0,0,0); \
  c0_ = __builtin_amdgcn_mfma_f32_16x16x32_bf16(A0_, bl00, c0_, 0,0,0); \
  c0_ = __builtin_amdgcn_mfma_f32_16x16x32_bf16(A1_, bl10, c0_, 0,0,0); \
  c1_ = __builtin_amdgcn_mfma_f32_16x16x32_bf16(A0_, bh01, c1_, 0,0,0); \
  c1_ = __builtin_amdgcn_mfma_f32_16x16x32_bf16(A1_, bh11, c1_, 0,0,0); \
  c1_ = __builtin_amdgcn_mfma_f32_16x16x32_bf16(A0_, bl01, c1_, 0,0,0); \
  c1_ = __builtin_amdgcn_mfma_f32_16x16x32_bf16(A1_, bl11, c1_, 0,0,0); \
  acc0[0]+=fmaxf(c0_[0],0.f); acc0[1]+=fmaxf(c0_[1],0.f); \
  acc0[2]+=fmaxf(c0_[2],0.f); acc0[3]+=fmaxf(c0_[3],0.f); \
  acc1[0]+=fmaxf(c1_[0],0.f); acc1[1]+=fmaxf(c1_[1],0.f); \
  acc1[2]+=fmaxf(c1_[2],0.f); acc1[3]+=fmaxf(c1_[3],0.f); \
} while(0)

// 48 rows = 3 M-tiles (rows 36..47 are permanently zero -> corrected later).
#define PHASEB3 do { \
  LFENCE; \
  _Pragma("unroll") \
  for (int t_ = 0; t_ < 3; ++t_) { \
    short8 A0_ = *(const short8*)&wb[t_ * 1024 + e0i]; \
    short8 A1_ = *(const short8*)&wb[t_ * 1024 + e1i]; \
    MFMA8(A0_, A1_); \
  } \
} while(0)

// One chunk: build 36 rows, fence, 3-tile MFMA.
#define CH1(A0,A1,A2, M0,M1,M2) do { SGR(A0,A1,A2, M0,M1,M2); PHASEB3; } while(0)

#define MKB(dst_h, dst_l, KH, NIDX) do { \
  _Pragma("unroll") \
  for (int e_ = 0; e_ < 8; ++e_) { \
    float f_ = W2[((KH)*32 + kg*8 + e_)*32 + 16*(NIDX) + colb]; \
    __hip_bfloat16 hi_ = __float2bfloat16(f_); \
    float lof_ = f_ - __bfloat162float(hi_); \
    __hip_bfloat16 lo_ = __float2bfloat16(lof_); \
    dst_h[e_] = *(short*)&hi_; dst_l[e_] = *(short*)&lo_; \
  } \
} while(0)

// launch_bounds(256,2): cap 256 VGPR (kernel needs ~130-170), 2 blocks/CU
// = 8 waves/CU. (256,4) in round 5 squeezed to 64 VGPR -> 120 MB scratch
// spill traffic, 2x regression. Occupancy 2/SIMD is the spill-free max here.
__global__ __launch_bounds__(256, 2) void symm_mlp_kernel(
    const float* __restrict__ x,
    const float* __restrict__ W1, const float* __restrict__ b1,
    const float* __restrict__ W2, const float* __restrict__ b2,
    const float* __restrict__ W3, const float* __restrict__ b3,
    const int* __restrict__ idx, const int* __restrict__ perms,
    float* __restrict__ out)
{
    __shared__ short h1s[4][48 * 64];     // per-wave 48-row buffer (6144 B each)
    __shared__ float redbuf[4][32];

    const int tid   = threadIdx.x;
    const int lane  = tid & 63;
    const int wv    = tid >> 6;
    const int batch = blockIdx.x;

    // ---- per-lane P[k*6+j] = pts[k] . W1[3j:3j+3, h=lane] (all registers) ----
    float P[36];
    {
        float w1c[18];
        #pragma unroll
        for (int r = 0; r < 18; ++r) w1c[r] = W1[r * 64 + lane];

        float px[6][3];
        #pragma unroll
        for (int k = 0; k < 6; ++k) {
            int p = idx[batch * 6 + k];
            #pragma unroll
            for (int d = 0; d < 3; ++d) px[k][d] = x[(batch * NN + p) * 3 + d];
        }
        #pragma unroll
        for (int k = 0; k < 6; ++k)
        #pragma unroll
        for (int j = 0; j < 6; ++j)
            P[k*6+j] = fmaf(px[k][2], w1c[3*j+2], fmaf(px[k][1], w1c[3*j+1], px[k][0] * w1c[3*j+0]));
    }
    const float b1v = b1[lane];

    // ---- W2 B-fragments (hi+lo bf16 split) ----
    const int colb = lane & 15, kg = lane >> 4;
    short8 bh00, bl00, bh10, bl10, bh01, bl01, bh11, bl11;
    MKB(bh00, bl00, 0, 0);
    MKB(bh10, bl10, 1, 0);
    MKB(bh01, bl01, 0, 1);
    MKB(bh11, bl11, 1, 1);
    const float b2v0 = b2[colb];
    const float b2v1 = b2[16 + colb];

    // ---- zero the pad rows 36..47 of this wave's buffer (stays zero all kernel) ----
    short* wb = &h1s[wv][0];
    *reinterpret_cast<u32x4*>(&wb[2304 + lane * 8]) = u32x4{0u, 0u, 0u, 0u};  // bytes 4608..5632
    *reinterpret_cast<u32x2*>(&wb[2816 + lane * 4]) = u32x2{0u, 0u};          // bytes 5632..6144

    // A-fragment bases (t-invariant swizzle: 16t = 0 mod 8)
    const int Xl  = (lane & 7) << 3;
    const int e0i = (lane & 15) * 64 + ((kg * 8) ^ Xl);
    const int e1i = (lane & 15) * 64 + ((32 + kg * 8) ^ Xl);

    f32x4 acc0 = {0.f,0.f,0.f,0.f}, acc1 = {0.f,0.f,0.f,0.f};

    // ---- 5 supergroups per wave (all 20 covered exactly once) ----
    if (wv == 0) {
        CH1(0,1,2, 3,4,5);  CH1(0,1,3, 2,4,5);  CH1(0,1,4, 2,3,5);
        CH1(0,1,5, 2,3,4);  CH1(0,2,3, 1,4,5);
    } else if (wv == 1) {
        CH1(0,2,4, 1,3,5);  CH1(0,2,5, 1,3,4);  CH1(0,3,4, 1,2,5);
        CH1(0,3,5, 1,2,4);  CH1(0,4,5, 1,2,3);
    } else if (wv == 2) {
        CH1(1,2,3, 0,4,5);  CH1(1,2,4, 0,3,5);  CH1(1,2,5, 0,3,4);
        CH1(1,3,4, 0,2,5);  CH1(1,3,5, 0,2,4);
    } else {
        CH1(1,4,5, 0,2,3);  CH1(2,3,4, 0,1,5);  CH1(2,3,5, 0,1,4);
        CH1(2,4,5, 0,1,3);  CH1(3,4,5, 0,1,2);
    }

    // ---- wave-level reduce (sum over this wave's 180 real + 60 pad rows) ----
    float s0 = acc0[0] + acc0[1] + acc0[2] + acc0[3];
    float s1 = acc1[0] + acc1[1] + acc1[2] + acc1[3];
    s0 += __shfl_xor(s0, 16, 64);  s0 += __shfl_xor(s0, 32, 64);
    s1 += __shfl_xor(s1, 16, 64);  s1 += __shfl_xor(s1, 32, 64);
    // pad rows contributed relu(b2[col]) each: 5 chunks x 12 rows = 60
    s0 -= 60.0f * fmaxf(b2v0, 0.0f);
    s1 -= 60.0f * fmaxf(b2v1, 0.0f);

    if (lane < 16)       redbuf[wv][lane]      = s0;
    else if (lane < 32)  redbuf[wv][lane]      = s1;   // lane-16 -> col 16+(lane&15)
    __syncthreads();

    // ---- combine waves + layer 3, once per batch ----
    if (tid < 40) {
        float m[32];
        #pragma unroll
        for (int c = 0; c < 32; ++c)
            m[c] = (redbuf[0][c] + redbuf[1][c] + redbuf[2][c] + redbuf[3][c]) * (1.0f / 720.0f);
        float y = b3[tid];
        #pragma unroll
        for (int c = 0; c < 32; ++c) y = fmaf(m[c], W3[c * 40 + tid], y);
        out[batch * 40 + tid] = y;
    }
}

extern "C" void kernel_launch(void* const* d_in, const int* in_sizes, int n_in,
                              void* d_out, int out_size, void* d_ws, size_t ws_size,
                              hipStream_t stream) {
    const float* x  = (const float*)d_in[0];
    const float* W1 = (const float*)d_in[1];
    const float* b1 = (const float*)d_in[2];
    const float* W2 = (const float*)d_in[3];
    const float* b2 = (const float*)d_in[4];
    const float* W3 = (const float*)d_in[5];
    const float* b3 = (const float*)d_in[6];
    const int* idx   = (const int*)d_in[7];
    const int* perms = (const int*)d_in[8];
    (void)perms;  // compile-time constant (all perms of 0..5, mean is order-invariant)
    float* out = (float*)d_out;

    symm_mlp_kernel<<<1024, 256, 0, stream>>>(x, W1, b1, W2, b2, W3, b3, idx, perms, out);
}